// Round 8
// baseline (297.157 us; speedup 1.0000x reference)
//
#include <hip/hip_runtime.h>
#include <hip/hip_bf16.h>

#define SIZE 1024
#define NH 16
#define HD 64
#define BB 2
#define SS 2048
#define MROWS (BB * SS)  // 4096
#define QT 128           // attn q-tile
#define NQT (SS / QT)    // 16 q-tiles per (b,h)
#define KT32 32          // attn k-tile (keys per iteration)
#define NKT2 ((SS / 2) / KT32)  // 32 k-tiles per S-half

using bf16 = __hip_bfloat16;
using frag16 = __attribute__((ext_vector_type(8))) short;   // 8 bf16 (4 VGPRs)
using f32x4 = __attribute__((ext_vector_type(4))) float;    // 4 fp32 acc
typedef unsigned int u32;

// async global->LDS, 16B per lane; lds dest = wave-uniform base + lane*16 (m97/m104)
__device__ __forceinline__ void glds16(const bf16* g, bf16* l) {
    __builtin_amdgcn_global_load_lds(
        (const __attribute__((address_space(1))) u32*)g,
        (__attribute__((address_space(3))) u32*)l, 16, 0, 0);
}

__device__ __forceinline__ void cvt_store8(bf16* dst, const float* src) {
    float4 a = *(const float4*)src;
    float4 b = *(const float4*)(src + 4);
    bf16 t[8];
    t[0] = __float2bfloat16(a.x); t[1] = __float2bfloat16(a.y);
    t[2] = __float2bfloat16(a.z); t[3] = __float2bfloat16(a.w);
    t[4] = __float2bfloat16(b.x); t[5] = __float2bfloat16(b.y);
    t[6] = __float2bfloat16(b.z); t[7] = __float2bfloat16(b.w);
    *(uint4*)dst = *(const uint4*)t;
}

// ---------------------------------------------------------------------------
// Weights-only fp32 -> bf16 cast (activations now consumed fp32 by qkv).
// ---------------------------------------------------------------------------
__global__ __launch_bounds__(256) void cast_w_kernel(
    const float* __restrict__ Wq, const float* __restrict__ Wk,
    const float* __restrict__ Wv, const float* __restrict__ Wo,
    bf16* __restrict__ Wb)
{
    const float* srcs[4] = {Wq, Wk, Wv, Wo};
    const float* s = srcs[blockIdx.z];
    bf16* d = Wb + (size_t)blockIdx.z * SIZE * SIZE;
    const int i = (blockIdx.x * 256 + threadIdx.x) * 8;   // grid.x = 512
    cvt_store8(d + i, s + i);
}

// ---------------------------------------------------------------------------
// QKV projection: A (activations) staged fp32->bf16 via VGPR cvt (A-side only),
// B (weights, pre-cast bf16) via glds16. 128x128 tile, BK=32.
// vt_mode: epilogue transposes via LDS -> vt[b][h][d][s] coalesced.
// ---------------------------------------------------------------------------
__global__ __launch_bounds__(256) void qkv_proj_kernel(
    const float* __restrict__ q, const float* __restrict__ k, const float* __restrict__ v,
    const bf16* __restrict__ Wb,
    const float* __restrict__ bq, const float* __restrict__ bk, const float* __restrict__ bv,
    bf16* __restrict__ qh, bf16* __restrict__ kh, bf16* __restrict__ vt)
{
    __shared__ __align__(16) bf16 smem[8704];   // As[4096] | Bs[4096]; reused as tr[64][136]
    bf16* As = smem;
    bf16* Bs = smem + 4096;

    const float *X, *bi; const bf16* W; bf16* Y; float scale; bool vm;
    if (blockIdx.z == 0)      { X = q; W = Wb;                   bi = bq; Y = qh; scale = 0.125f; vm = false; }
    else if (blockIdx.z == 1) { X = k; W = Wb + SIZE * SIZE;     bi = bk; Y = kh; scale = 1.0f;   vm = false; }
    else                      { X = v; W = Wb + 2 * SIZE * SIZE; bi = bv; Y = vt; scale = 1.0f;   vm = true;  }

    const int tid = threadIdx.x;
    const int wave = tid >> 6;
    const int lane = tid & 63;
    const int lane15 = lane & 15;
    const int quad = lane >> 4;
    const int bm = blockIdx.y * 128;
    const int bn = blockIdx.x * 128;
    const int wm = (wave & 1) * 64;
    const int wn = (wave >> 1) * 64;

    f32x4 acc[4][4];
#pragma unroll
    for (int i = 0; i < 4; i++)
#pragma unroll
        for (int j = 0; j < 4; j++)
            acc[i][j] = (f32x4){0.f, 0.f, 0.f, 0.f};

    const int r0 = tid >> 2, c0 = (tid & 3) * 8, r1 = r0 + 64;
    const float* xp0 = X + (size_t)(bm + r0) * SIZE + c0;
    const float* xp1 = X + (size_t)(bm + r1) * SIZE + c0;
    const int srow = lane >> 2;        // B staging: 0..15 within chunk
    const int scol = (lane & 3) * 8;

    for (int kt = 0; kt < SIZE / 32; kt++) {
        const int k0 = kt * 32;
        __syncthreads();
        // A loads first (oldest in vmcnt queue -> cvt waits only on these)
        float4 fa0[2], fa1[2];
        fa0[0] = *(const float4*)(xp0 + k0); fa0[1] = *(const float4*)(xp0 + k0 + 4);
        fa1[0] = *(const float4*)(xp1 + k0); fa1[1] = *(const float4*)(xp1 + k0 + 4);
#pragma unroll
        for (int n = 0; n < 2; n++) {
            const int c = wave * 2 + n;
            glds16(W + (size_t)(bn + c * 16 + srow) * SIZE + k0 + scol, Bs + c * 512);
        }
        cvt_store8(As + r0 * 32 + c0, (const float*)fa0);
        cvt_store8(As + r1 * 32 + c0, (const float*)fa1);
        __syncthreads();

        frag16 a[4], b[4];
#pragma unroll
        for (int mi = 0; mi < 4; mi++)
            a[mi] = *(const frag16*)(As + (wm + mi * 16 + lane15) * 32 + quad * 8);
#pragma unroll
        for (int ni = 0; ni < 4; ni++)
            b[ni] = *(const frag16*)(Bs + (wn + ni * 16 + lane15) * 32 + quad * 8);
#pragma unroll
        for (int mi = 0; mi < 4; mi++)
#pragma unroll
            for (int ni = 0; ni < 4; ni++)
                acc[mi][ni] = __builtin_amdgcn_mfma_f32_16x16x32_bf16(
                    a[mi], b[ni], acc[mi][ni], 0, 0, 0);
    }

    if (!vm) {
#pragma unroll
        for (int ni = 0; ni < 4; ni++) {
            const int col = bn + wn + ni * 16 + lane15;
            const float bv = bi[col];
#pragma unroll
            for (int mi = 0; mi < 4; mi++) {
                const int row = bm + wm + mi * 16 + quad * 4;
#pragma unroll
                for (int r = 0; r < 4; r++)
                    Y[(size_t)(row + r) * SIZE + col] =
                        __float2bfloat16((acc[mi][ni][r] + bv) * scale);
            }
        }
    } else {
        bf16* tr = smem;                   // [64][136]
        const int bloc = bm >> 11;
        const int s0g = bm & (SS - 1);
#pragma unroll
        for (int p = 0; p < 2; p++) {
            __syncthreads();
            if ((wave >> 1) == p) {
#pragma unroll
                for (int ni = 0; ni < 4; ni++) {
                    const int colp = ni * 16 + lane15;
                    const float bv = bi[bn + p * 64 + colp];
#pragma unroll
                    for (int mi = 0; mi < 4; mi++) {
                        const int row = wm + mi * 16 + quad * 4;
#pragma unroll
                        for (int r = 0; r < 4; r++)
                            tr[colp * 136 + row + r] =
                                __float2bfloat16(acc[mi][ni][r] + bv);
                    }
                }
            }
            __syncthreads();
            const int colp = tid >> 2;
            const int gcol = bn + p * 64 + colp;
            const int hh = gcol >> 6, dd = gcol & (HD - 1);
            bf16* dst = (bf16*)Y + ((size_t)(bloc * NH + hh) * HD + dd) * SS
                        + s0g + (tid & 3) * 32;
            const bf16* src = tr + colp * 136 + (tid & 3) * 32;
#pragma unroll
            for (int j = 0; j < 4; j++)
                *(uint4*)(dst + j * 8) = *(const uint4*)(src + j * 8);
        }
    }
}

// ---------------------------------------------------------------------------
// Flash attention, split-S, 32-key tiles DOUBLE-BUFFERED via glds16:
// stage(kt+1) after barrier -> compute(kt) -> barrier. One barrier per kt;
// the vmcnt drain lands after a full compute phase (latency hidden).
// XOR-swizzled LDS rows (glds16 forbids padding): Ks 16B-groups g^(row&7),
// Vs g^(row&3). S^T = K Q^T packed P store; l = P @ ones via MFMA.
// ---------------------------------------------------------------------------
__global__ __launch_bounds__(256) void attn_kernel(
    const bf16* __restrict__ qh, const bf16* __restrict__ kh,
    const bf16* __restrict__ vt, bf16* __restrict__ po, float* __restrict__ pl)
{
    __shared__ __align__(16) bf16 Ks[2][KT32 * 64];   // swizzled [key][d]
    __shared__ __align__(16) bf16 Vs[2][64 * KT32];   // swizzled [d][s]
    __shared__ __align__(16) bf16 Ps[4][32 * 40];     // per-wave P [q][key], +8 pad

    const int tid = threadIdx.x;
    const int wave = tid >> 6;
    const int lane = tid & 63;
    const int lane15 = lane & 15;
    const int quad = lane >> 4;

    const int b = blockIdx.z, h = blockIdx.y;
    const int qt = blockIdx.x >> 1;
    const int sh = blockIdx.x & 1;
    const int q0 = qt * QT;

    const size_t baseq = (size_t)b * SS * SIZE + (size_t)h * HD;
    const size_t basev = (size_t)(b * NH + h) * HD * SS;
    const float LOG2E = 1.44269504088896340736f;
    const float OFF = 12.0f * LOG2E;

    frag16 aq[2][2];
#pragma unroll
    for (int m = 0; m < 2; m++) {
        const int qrow = q0 + wave * 32 + m * 16 + lane15;
        const bf16* qp = qh + baseq + (size_t)qrow * SIZE + quad * 8;
        aq[m][0] = *(const frag16*)(qp);
        aq[m][1] = *(const frag16*)(qp + 32);
    }

    frag16 bones;
#pragma unroll
    for (int e = 0; e < 8; e++) bones[e] = (short)0x3F80;   // bf16 1.0

    f32x4 ofrag[2][4], l_frag[2];
#pragma unroll
    for (int m = 0; m < 2; m++) {
        l_frag[m] = (f32x4){0.f, 0.f, 0.f, 0.f};
#pragma unroll
        for (int dt = 0; dt < 4; dt++) ofrag[m][dt] = (f32x4){0.f, 0.f, 0.f, 0.f};
    }

    const int krow = wave * 8 + (lane >> 3);                 // key row 0..31
    const int kgl  = ((lane & 7) ^ ((lane >> 3) & 7)) * 8;   // swizzled d-group
    const int vrow = wave * 16 + (lane >> 2);                // d row 0..63
    const int vgl  = ((lane & 3) ^ ((lane >> 2) & 3)) * 8;   // swizzled s-group
    const int s00 = sh * (SS / 2);

#define STAGE(BUF, KT)                                                          \
    {                                                                           \
        const int s0_ = s00 + (KT) * KT32;                                      \
        glds16(kh + baseq + (size_t)(s0_ + krow) * SIZE + kgl,                  \
               &Ks[BUF][wave * 512]);                                           \
        glds16(vt + basev + (size_t)vrow * SS + s0_ + vgl,                      \
               &Vs[BUF][wave * 512]);                                           \
    }

    STAGE(0, 0);
    __syncthreads();

    for (int kt = 0; kt < NKT2; kt++) {
        const int cur = kt & 1;
        if (kt + 1 < NKT2) STAGE(cur ^ 1, kt + 1);

        frag16 kf[2][2];
#pragma unroll
        for (int nt = 0; nt < 2; nt++) {
            const int row = nt * 16 + lane15;
#pragma unroll
            for (int c2 = 0; c2 < 2; c2++) {
                const int pg = (c2 * 4 + quad) ^ (row & 7);
                kf[nt][c2] = *(const frag16*)(&Ks[cur][0] + row * 64 + pg * 8);
            }
        }

#pragma unroll
        for (int m = 0; m < 2; m++) {
#pragma unroll
            for (int nt = 0; nt < 2; nt++) {
                f32x4 c = (f32x4){0.f, 0.f, 0.f, 0.f};
                c = __builtin_amdgcn_mfma_f32_16x16x32_bf16(kf[nt][0], aq[m][0], c, 0, 0, 0);
                c = __builtin_amdgcn_mfma_f32_16x16x32_bf16(kf[nt][1], aq[m][1], c, 0, 0, 0);
                bf16 p4[4];
#pragma unroll
                for (int r = 0; r < 4; r++)
                    p4[r] = __float2bfloat16(exp2f(fminf(c[r], 30.f) * LOG2E - OFF));
                *(uint2*)(&Ps[wave][0] + (m * 16 + lane15) * 40 + nt * 16 + quad * 4) =
                    *(const uint2*)p4;
            }
        }
        __builtin_amdgcn_wave_barrier();

        frag16 ap[2];
#pragma unroll
        for (int m = 0; m < 2; m++)
            ap[m] = *(const frag16*)(&Ps[wave][0] + (m * 16 + lane15) * 40 + quad * 8);

#pragma unroll
        for (int m = 0; m < 2; m++)
            l_frag[m] = __builtin_amdgcn_mfma_f32_16x16x32_bf16(ap[m], bones, l_frag[m], 0, 0, 0);

#pragma unroll
        for (int dt = 0; dt < 4; dt++) {
            const int row = dt * 16 + lane15;
            const int pg = quad ^ (row & 3);
            frag16 bv = *(const frag16*)(&Vs[cur][0] + row * 32 + pg * 8);
#pragma unroll
            for (int m = 0; m < 2; m++)
                ofrag[m][dt] = __builtin_amdgcn_mfma_f32_16x16x32_bf16(ap[m], bv, ofrag[m][dt], 0, 0, 0);
        }

        __syncthreads();
    }
#undef STAGE

    const int pb = ((b * NH + h) * NQT + qt) * 2 + sh;
    if (lane15 == 0) {
        float* plp = pl + (size_t)pb * QT;
#pragma unroll
        for (int m = 0; m < 2; m++)
#pragma unroll
            for (int r = 0; r < 4; r++)
                plp[wave * 32 + m * 16 + quad * 4 + r] = l_frag[m][r];
    }
    bf16* pop = po + (size_t)pb * QT * HD;
#pragma unroll
    for (int m = 0; m < 2; m++)
#pragma unroll
        for (int dt = 0; dt < 4; dt++)
#pragma unroll
            for (int r = 0; r < 4; r++)
                pop[(size_t)(wave * 32 + m * 16 + quad * 4 + r) * HD + dt * 16 + lane15] =
                    __float2bfloat16(ofrag[m][dt][r]);
}

// ---------------------------------------------------------------------------
// Output projection with fused split-S combine in A-staging; W via glds16.
// BM=64 x BN=128 -> 512 blocks = 2/CU. fp32 out.
// ---------------------------------------------------------------------------
__global__ __launch_bounds__(256) void out_proj_kernel(
    const bf16* __restrict__ po, const float* __restrict__ pl,
    const bf16* __restrict__ Wob, const float* __restrict__ bo,
    float* __restrict__ out)
{
    __shared__ __align__(16) bf16 As[64 * 32];
    __shared__ __align__(16) bf16 Bs[128 * 32];

    const int tid = threadIdx.x;
    const int wave = tid >> 6;
    const int lane = tid & 63;
    const int lane15 = lane & 15;
    const int quad = lane >> 4;
    const int bm = blockIdx.y * 64;
    const int bn = blockIdx.x * 128;
    const int wn = wave * 32;

    f32x4 acc[4][2];
#pragma unroll
    for (int i = 0; i < 4; i++)
#pragma unroll
        for (int j = 0; j < 2; j++)
            acc[i][j] = (f32x4){0.f, 0.f, 0.f, 0.f};

    const int ar = tid >> 2, ac = (tid & 3) * 8;
    const int gm = bm + ar;
    const int bb = gm >> 11, s = gm & (SS - 1);
    const int qtile = s >> 7, qr = s & (QT - 1);
    const int tbase = (bb * NH) * NQT + qtile;
    const int srow = lane >> 2, scol = (lane & 3) * 8;

    for (int kt = 0; kt < SIZE / 32; kt++) {
        const int k0 = kt * 32;
        __syncthreads();
        {
            const int hh = k0 >> 6;
            const size_t tile = (size_t)(tbase + hh * NQT) * 2;
            const int d = (k0 & 32) + ac;
            uint4 u0 = *(const uint4*)(po + ((tile + 0) * QT + qr) * HD + d);
            uint4 u1 = *(const uint4*)(po + ((tile + 1) * QT + qr) * HD + d);
            const float l = pl[(tile + 0) * QT + qr] + pl[(tile + 1) * QT + qr];
            const float inv = 1.0f / fmaxf(l, 1e-30f);
            const bf16* a0 = (const bf16*)&u0;
            const bf16* a1 = (const bf16*)&u1;
            bf16 t[8];
#pragma unroll
            for (int e = 0; e < 8; e++)
                t[e] = __float2bfloat16(
                    (__bfloat162float(a0[e]) + __bfloat162float(a1[e])) * inv);
            *(uint4*)(As + ar * 32 + ac) = *(const uint4*)t;
        }
#pragma unroll
        for (int n = 0; n < 2; n++) {
            const int c = wave * 2 + n;
            glds16(Wob + (size_t)(bn + c * 16 + srow) * SIZE + k0 + scol, Bs + c * 512);
        }
        __syncthreads();

        frag16 a[4], b[2];
#pragma unroll
        for (int mi = 0; mi < 4; mi++)
            a[mi] = *(const frag16*)(As + (mi * 16 + lane15) * 32 + quad * 8);
#pragma unroll
        for (int ni = 0; ni < 2; ni++)
            b[ni] = *(const frag16*)(Bs + (wn + ni * 16 + lane15) * 32 + quad * 8);
#pragma unroll
        for (int mi = 0; mi < 4; mi++)
#pragma unroll
            for (int ni = 0; ni < 2; ni++)
                acc[mi][ni] = __builtin_amdgcn_mfma_f32_16x16x32_bf16(
                    a[mi], b[ni], acc[mi][ni], 0, 0, 0);
    }

#pragma unroll
    for (int ni = 0; ni < 2; ni++) {
        const int col = bn + wn + ni * 16 + lane15;
        const float bv = bo[col];
#pragma unroll
        for (int mi = 0; mi < 4; mi++) {
            const int row = bm + mi * 16 + quad * 4;
#pragma unroll
            for (int r = 0; r < 4; r++)
                out[(size_t)(row + r) * SIZE + col] = acc[mi][ni][r] + bv;
        }
    }
}

extern "C" void kernel_launch(void* const* d_in, const int* in_sizes, int n_in,
                              void* d_out, int out_size, void* d_ws, size_t ws_size,
                              hipStream_t stream) {
    const float* q  = (const float*)d_in[0];
    const float* k  = (const float*)d_in[1];
    const float* v  = (const float*)d_in[2];
    const float* Wq = (const float*)d_in[3];
    const float* bq = (const float*)d_in[4];
    const float* Wk = (const float*)d_in[5];
    const float* bk = (const float*)d_in[6];
    const float* Wv = (const float*)d_in[7];
    const float* bv = (const float*)d_in[8];
    const float* Wo = (const float*)d_in[9];
    const float* bo = (const float*)d_in[10];
    float* out = (float*)d_out;

    // ws (bf16): Wb[4M] | qh | kh | vt (4.19M each) | po (8.39M) | pl (131072 f32)
    bf16* Wb = (bf16*)d_ws;
    bf16* qh = Wb + (size_t)4 * SIZE * SIZE;
    bf16* kh = qh + (size_t)MROWS * SIZE;
    bf16* vt = kh + (size_t)MROWS * SIZE;
    bf16* po = vt + (size_t)MROWS * SIZE;
    float* pl = (float*)(po + (size_t)1024 * QT * HD);

    cast_w_kernel<<<dim3(SIZE * SIZE / 2048, 1, 4), 256, 0, stream>>>(
        Wq, Wk, Wv, Wo, Wb);
    qkv_proj_kernel<<<dim3(SIZE / 128, MROWS / 128, 3), 256, 0, stream>>>(
        q, k, v, Wb, bq, bk, bv, qh, kh, vt);
    attn_kernel<<<dim3(NQT * 2, NH, BB), 256, 0, stream>>>(qh, kh, vt, po, pl);
    out_proj_kernel<<<dim3(SIZE / 128, MROWS / 64, 1), 256, 0, stream>>>(
        po, pl, Wb + (size_t)3 * SIZE * SIZE, bo, out);
}